// Round 4
// baseline (5187.706 us; speedup 1.0000x reference)
//
#include <hip/hip_runtime.h>

typedef unsigned short u16;
typedef unsigned int u32;
typedef __attribute__((ext_vector_type(8))) short bf16x8;
typedef __attribute__((ext_vector_type(4))) float f32x4;

#define SB 16
#define SS 2048
#define SD 256
#define CC 16            // chunk length
#define NCH (SS / CC)    // 128 chunks
#define KAPPA 4.8828125e-6f   // 0.01 * 2/(16*256)

__device__ __forceinline__ u16 f2bf(float f) {
  u32 u = __float_as_uint(f);
  u = (u + 0x7FFFu + ((u >> 16) & 1u)) >> 16;
  return (u16)u;
}
__device__ __forceinline__ float bf2f(u16 u) { return __uint_as_float((u32)u << 16); }

__device__ __forceinline__ bf16x8 ldfrag(const u16* p) {
  union { uint4 u; bf16x8 f; } cv;
  cv.u = *(const uint4*)p;
  return cv.f;
}
__device__ __forceinline__ f32x4 mfma16(bf16x8 a, bf16x8 b, f32x4 c) {
  return __builtin_amdgcn_mfma_f32_16x16x32_bf16(a, b, c, 0, 0, 0);
}

// ---------------- prep: train/state (bf16 [t][b][d]) + trainT ([t][d][b]) ----
__global__ __launch_bounds__(256) void prep_kernel(
    const float* __restrict__ x, const float* __restrict__ noise,
    const float* __restrict__ a1,
    u16* __restrict__ train, u16* __restrict__ state, u16* __restrict__ trainT) {
  size_t i4 = (size_t)blockIdx.x * 256 + threadIdx.x;
  size_t base = i4 * 4;
  int d = (int)(base & 255);
  int t = (int)((base >> 8) & 2047);
  int b = (int)(base >> 19);
  float4 xv = *(const float4*)(x + base);
  float4 nv = *(const float4*)(noise + base);
  float4 av = *(const float4*)(a1 + d);
  float m0 = tanhf(av.x * xv.x);
  float m1 = tanhf(av.y * xv.y);
  float m2 = tanhf(av.z * xv.z);
  float m3 = tanhf(av.w * xv.w);
  size_t dst = ((size_t)t * SB + b) * SD + d;
  ushort4 tr, st;
  tr.x = f2bf(m0 + nv.x); tr.y = f2bf(m1 + nv.y);
  tr.z = f2bf(m2 + nv.z); tr.w = f2bf(m3 + nv.w);
  st.x = f2bf(m0); st.y = f2bf(m1); st.z = f2bf(m2); st.w = f2bf(m3);
  *(ushort4*)(train + dst) = tr;
  *(ushort4*)(state + dst) = st;
  size_t tb = ((size_t)t * SD + d) * SB + b;   // trainT[t][d][b]
  trainT[tb + 0 * SB] = tr.x;
  trainT[tb + 1 * SB] = tr.y;
  trainT[tb + 2 * SB] = tr.z;
  trainT[tb + 3 * SB] = tr.w;
}

// ---------------- gram2: AG[c][t][sp][16][32], LbG likewise (zero-filled) ----
// AG half h: A[t,s=2sp+h] = tr_t @ tr_s^T (valid s<t, else 0)
// LbG half h: Lb[t,s] = st_t @ tr_s^T (valid s<=t, else 0)
__global__ __launch_bounds__(256) void gram2_kernel(
    const u16* __restrict__ tr, const u16* __restrict__ st,
    u16* __restrict__ AG, u16* __restrict__ LbG) {
  const int cb = blockIdx.x;        // c*16 + t
  const int c = cb >> 4, t = cb & 15;
  const int tid = threadIdx.x, lane = tid & 63, wv = tid >> 6;
  const int lr = lane & 15, lq = lane >> 4;
  const size_t Tt = (size_t)cb;     // global step of t
  bf16x8 trF[8], stF[8];
#pragma unroll
  for (int k = 0; k < 8; ++k) {
    trF[k] = ldfrag(tr + (Tt * 16 + lr) * 256 + k * 32 + lq * 8);
    stF[k] = ldfrag(st + (Tt * 16 + lr) * 256 + k * 32 + lq * 8);
  }
  for (int ii = 0; ii < 2; ++ii) {
    const int sp = wv + ii * 4;
    u16* dA = AG + ((size_t)cb * 8 + sp) * 512;
    u16* dL = LbG + ((size_t)cb * 8 + sp) * 512;
#pragma unroll
    for (int h = 0; h < 2; ++h) {
      const int s = 2 * sp + h;
      f32x4 accA = {0.f, 0.f, 0.f, 0.f}, accL = {0.f, 0.f, 0.f, 0.f};
      if (s <= t) {
        const u16* bsrc = tr + ((size_t)(c * 16 + s) * 16 + lr) * 256 + lq * 8;
#pragma unroll
        for (int k = 0; k < 8; ++k) {
          bf16x8 bk = ldfrag(bsrc + k * 32);
          if (s < t) accA = mfma16(trF[k], bk, accA);
          accL = mfma16(stF[k], bk, accL);
        }
      }
#pragma unroll
      for (int r = 0; r < 4; ++r) {
        int idx = (lq * 4 + r) * 32 + h * 16 + lr;   // [row=b(t-side)][col]
        dA[idx] = (s < t) ? f2bf(accA[r]) : (u16)0;
        dL[idx] = (s <= t) ? f2bf(accL[r]) : (u16)0;
      }
    }
  }
}

// ---------------- ff path: out = u .* (v @ Wp^T) ----------------
__global__ __launch_bounds__(256) void ff_kernel(
    const float* __restrict__ x, const float* __restrict__ a2,
    const float* __restrict__ Wp, const float* __restrict__ ffa,
    const float* __restrict__ ffb, const float* __restrict__ ffg_,
    const float* __restrict__ ffe_, float* __restrict__ out) {
  __shared__ float As[32][68];
  __shared__ float Bs[32][68];
  const int tid = threadIdx.x;
  const int gm0 = blockIdx.x * 64;
  const int gn0 = blockIdx.y * 64;
  const int tm = tid & 15, tn = tid >> 4;
  const int lr = tid & 63;
  const int lq = tid >> 6;
  float acc[4][4];
#pragma unroll
  for (int i = 0; i < 4; i++)
#pragma unroll
    for (int j = 0; j < 4; j++) acc[i][j] = 0.f;

  for (int k0 = 0; k0 < 256; k0 += 32) {
    {
      const float* xp = x + (size_t)(gm0 + lr) * 256 + k0 + lq * 8;
      float4 v0 = *(const float4*)(xp);
      float4 v1 = *(const float4*)(xp + 4);
      const float* ap = a2 + k0 + lq * 8;
      float4 a0 = *(const float4*)(ap);
      float4 a1v = *(const float4*)(ap + 4);
      As[lq * 8 + 0][lr] = tanhf(a0.x * v0.x);
      As[lq * 8 + 1][lr] = tanhf(a0.y * v0.y);
      As[lq * 8 + 2][lr] = tanhf(a0.z * v0.z);
      As[lq * 8 + 3][lr] = tanhf(a0.w * v0.w);
      As[lq * 8 + 4][lr] = tanhf(a1v.x * v1.x);
      As[lq * 8 + 5][lr] = tanhf(a1v.y * v1.y);
      As[lq * 8 + 6][lr] = tanhf(a1v.z * v1.z);
      As[lq * 8 + 7][lr] = tanhf(a1v.w * v1.w);
      const float* wp = Wp + (size_t)(gn0 + lr) * 256 + k0 + lq * 8;
      float4 w0 = *(const float4*)(wp);
      float4 w1 = *(const float4*)(wp + 4);
      Bs[lq * 8 + 0][lr] = w0.x; Bs[lq * 8 + 1][lr] = w0.y;
      Bs[lq * 8 + 2][lr] = w0.z; Bs[lq * 8 + 3][lr] = w0.w;
      Bs[lq * 8 + 4][lr] = w1.x; Bs[lq * 8 + 5][lr] = w1.y;
      Bs[lq * 8 + 6][lr] = w1.z; Bs[lq * 8 + 7][lr] = w1.w;
    }
    __syncthreads();
#pragma unroll
    for (int k = 0; k < 32; ++k) {
      float4 av4 = *(const float4*)&As[k][tm * 4];
      float4 bv4 = *(const float4*)&Bs[k][tn * 4];
      float a[4] = {av4.x, av4.y, av4.z, av4.w};
      float b[4] = {bv4.x, bv4.y, bv4.z, bv4.w};
#pragma unroll
      for (int i = 0; i < 4; i++)
#pragma unroll
        for (int j = 0; j < 4; j++) acc[i][j] += a[i] * b[j];
    }
    __syncthreads();
  }
  const float ga = ffg_[0], et = ffe_[0];
#pragma unroll
  for (int ii = 0; ii < 4; ++ii) {
    int row = gm0 + tm * 4 + ii;
    int col = gn0 + tn * 4;
    float4 xv = *(const float4*)(x + (size_t)row * 256 + col);
    float4 fa = *(const float4*)(ffa + col);
    float4 fb = *(const float4*)(ffb + col);
    float4 a2v = *(const float4*)(a2 + col);
    float xs[4] = {xv.x, xv.y, xv.z, xv.w};
    float fas[4] = {fa.x, fa.y, fa.z, fa.w};
    float fbs[4] = {fb.x, fb.y, fb.z, fb.w};
    float a2s[4] = {a2v.x, a2v.y, a2v.z, a2v.w};
    float res[4];
#pragma unroll
    for (int j = 0; j < 4; ++j) {
      float v = tanhf(a2s[j] * xs[j]);
      float z = fas[j] * v;
      float gelu = 0.5f * z * (1.0f + erff(z * 0.70710678118654752f));
      float u = ga * gelu + et * sinf(fbs[j] * v);
      res[j] = u * acc[ii][j];
    }
    float4 o; o.x = res[0]; o.y = res[1]; o.z = res[2]; o.w = res[3];
    *(float4*)(out + (size_t)row * 256 + col) = o;
  }
}

// ---------------- scan: 16 WGs, 16 W-rows each, chunked Neumann-2 ----------
// Per chunk: P1 rhs/q MFMAs; P2 y1=L@rhs; P3 y2=L@y1, diff; P4 out+=Lb@Dp,
// dW = Tr^T@Dp, apply; all tiles [16-free][K] bf16, K=32 stacking 2 s-steps.
__global__ __launch_bounds__(256, 1) void scan_kernel(
    const u16* __restrict__ tr, const u16* __restrict__ st,
    const u16* __restrict__ trT, const u16* __restrict__ AG,
    const u16* __restrict__ LbG, const float* __restrict__ Wttt,
    float* __restrict__ out) {
  __shared__ u16 RpL[CC][16 * 24];   // bf16(rhs) transposed tiles [d1][b], row pad 24
  __shared__ u16 Y1L[CC][16 * 24];   // bf16(y1)
  __shared__ u16 DpL[CC][16 * 24];   // bf16(-kappa*diff)
  __shared__ u16 WbL[16][264];       // bf16 mirror of W block [d1][d]
  __shared__ float WfL[16][264];     // f32 master W block

  const int tid = threadIdx.x;
  const int lane = tid & 63;
  const int wv = tid >> 6;           // wave 0..3 owns t = wv*4 .. wv*4+3
  const int d1b = blockIdx.x;        // W-row block
  const int lr = lane & 15;
  const int lq = lane >> 4;

  for (int i = tid; i < 16 * 256; i += 256) {
    int r = i >> 8, d = i & 255;
    float w = Wttt[(size_t)(d1b * 16 + r) * 256 + d];
    WfL[r][d] = w;
    WbL[r][d] = f2bf(w);
  }
  __syncthreads();

  for (int c = 0; c < NCH; ++c) {
    f32x4 rhsF[4], y1F[4], outF[4];
#pragma unroll
    for (int i = 0; i < 4; ++i) {
      rhsF[i] = (f32x4){0.f, 0.f, 0.f, 0.f};
      y1F[i] = (f32x4){0.f, 0.f, 0.f, 0.f};
      outF[i] = (f32x4){0.f, 0.f, 0.f, 0.f};
    }

    // ---- P1: rhs[t] = tr_t@W^T - st_t ; q[t] = st_t@W^T (into outF) ----
#pragma unroll
    for (int i = 0; i < 4; ++i) {
      const int t = wv * 4 + i;
      const size_t T = (size_t)c * CC + t;
      const u16* trt = tr + (T * 16 + lr) * 256 + lq * 8;
      const u16* stt = st + (T * 16 + lr) * 256 + lq * 8;
      f32x4 racc = rhsF[i], qacc = outF[i];
#pragma unroll
      for (int k = 0; k < 8; ++k) {
        bf16x8 wb = ldfrag(&WbL[lr][k * 32 + lq * 8]);
        bf16x8 af = ldfrag(trt + k * 32);
        bf16x8 sf = ldfrag(stt + k * 32);
        racc = mfma16(af, wb, racc);
        qacc = mfma16(sf, wb, qacc);
      }
      // subtract st (tile element [b=lq*4+r][d1=lr])
#pragma unroll
      for (int r = 0; r < 4; ++r)
        racc[r] -= bf2f(st[(T * 16 + lq * 4 + r) * 256 + d1b * 16 + lr]);
      rhsF[i] = racc; outF[i] = qacc;
      ushort4 pk;
      pk.x = f2bf(racc.x); pk.y = f2bf(racc.y);
      pk.z = f2bf(racc.z); pk.w = f2bf(racc.w);
      *(ushort4*)(&RpL[t][lr * 24 + lq * 4]) = pk;   // transposed publish
    }
    __syncthreads();  // b1

    // ---- P2: y1[t] = sum_s A[t,s]@rhs[s] ----
#pragma unroll
    for (int i = 0; i < 4; ++i) {
      const int t = wv * 4 + i;
      const u16* ag = AG + (((size_t)c * 16 + t) * 8) * 512;
      f32x4 acc = y1F[i];
#pragma unroll
      for (int sp = 0; sp < 8; ++sp) {
        bf16x8 af = ldfrag(ag + sp * 512 + lr * 32 + lq * 8);
        bf16x8 bf = ldfrag(&RpL[2 * sp + (lq >> 1)][lr * 24 + (lq & 1) * 8]);
        acc = mfma16(af, bf, acc);
      }
      y1F[i] = acc;
      ushort4 pk;
      pk.x = f2bf(acc.x); pk.y = f2bf(acc.y);
      pk.z = f2bf(acc.z); pk.w = f2bf(acc.w);
      *(ushort4*)(&Y1L[t][lr * 24 + lq * 4]) = pk;
    }
    __syncthreads();  // b2

    // ---- P3: y2[t] = sum_s A[t,s]@y1[s]; diff; publish Dp = -kappa*diff ----
#pragma unroll
    for (int i = 0; i < 4; ++i) {
      const int t = wv * 4 + i;
      const u16* ag = AG + (((size_t)c * 16 + t) * 8) * 512;
      f32x4 acc = {0.f, 0.f, 0.f, 0.f};
#pragma unroll
      for (int sp = 0; sp < 8; ++sp) {
        bf16x8 af = ldfrag(ag + sp * 512 + lr * 32 + lq * 8);
        bf16x8 bf = ldfrag(&Y1L[2 * sp + (lq >> 1)][lr * 24 + (lq & 1) * 8]);
        acc = mfma16(af, bf, acc);
      }
      ushort4 pk;
#pragma unroll
      for (int r = 0; r < 4; ++r) {
        float dv = rhsF[i][r] - KAPPA * y1F[i][r] + (KAPPA * KAPPA) * acc[r];
        ((u16*)&pk)[r] = f2bf(-KAPPA * dv);
      }
      *(ushort4*)(&DpL[t][lr * 24 + lq * 4]) = pk;
    }
    __syncthreads();  // b3

    // ---- P4: Out[t] = q + sum_s Lb[t,s]@Dp[s]; store; dW = Tr^T@Dp ----
#pragma unroll
    for (int i = 0; i < 4; ++i) {
      const int t = wv * 4 + i;
      const size_t T = (size_t)c * CC + t;
      const u16* lb = LbG + (((size_t)c * 16 + t) * 8) * 512;
      f32x4 acc = outF[i];
#pragma unroll
      for (int sp = 0; sp < 8; ++sp) {
        bf16x8 af = ldfrag(lb + sp * 512 + lr * 32 + lq * 8);
        bf16x8 bf = ldfrag(&DpL[2 * sp + (lq >> 1)][lr * 24 + (lq & 1) * 8]);
        acc = mfma16(af, bf, acc);
      }
#pragma unroll
      for (int r = 0; r < 4; ++r) {
        size_t oi = ((size_t)(lq * 4 + r) * SS + T) * SD + d1b * 16 + lr;
        out[oi] += acc[r];
      }
    }
    // dW: wave owns d2 tiles wv*4 .. wv*4+3; K=(s,b) stacked over 8 MFMAs
#pragma unroll
    for (int j = 0; j < 4; ++j) {
      const int d2b = wv * 4 + j;
      f32x4 acc = {0.f, 0.f, 0.f, 0.f};
#pragma unroll
      for (int sp = 0; sp < 8; ++sp) {
        const int s0 = 2 * sp + (lq >> 1);
        bf16x8 af = ldfrag(&DpL[s0][lr * 24 + (lq & 1) * 8]);
        bf16x8 bf = ldfrag(trT + ((size_t)(c * CC + s0) * 256 + d2b * 16 + lr) * 16 +
                           (lq & 1) * 8);
        acc = mfma16(af, bf, acc);
      }
      // apply: D[d1=lq*4+r][d2=d2b*16+lr]
#pragma unroll
      for (int r = 0; r < 4; ++r)
        WfL[lq * 4 + r][d2b * 16 + lr] += acc[r];
    }
    __syncthreads();  // b4: all dW applied

    for (int i = tid; i < 16 * 256; i += 256)
      WbL[i >> 8][i & 255] = f2bf(WfL[i >> 8][i & 255]);
    __syncthreads();  // b5: Wb ready for next chunk
  }
}

extern "C" void kernel_launch(void* const* d_in, const int* in_sizes, int n_in,
                              void* d_out, int out_size, void* d_ws, size_t ws_size,
                              hipStream_t stream) {
  const float* x     = (const float*)d_in[0];
  const float* noise = (const float*)d_in[1];
  const float* a1    = (const float*)d_in[2];
  const float* a2    = (const float*)d_in[3];
  const float* Wttt  = (const float*)d_in[4];
  const float* Wproj = (const float*)d_in[5];
  const float* ffa   = (const float*)d_in[6];
  const float* ffb   = (const float*)d_in[7];
  const float* ffg   = (const float*)d_in[8];
  const float* ffe   = (const float*)d_in[9];
  float* out = (float*)d_out;

  const size_t N = (size_t)SB * SS * SD;   // 8388608 elements
  u16* tr  = (u16*)d_ws;
  u16* st  = tr + N;
  u16* trT = st + N;
  u16* AG  = trT + N;   // NCH*CC*8*512 = N ushorts
  u16* LbG = AG + N;    // total ws = 5N*2B ~ 84MB

  prep_kernel<<<8192, 256, 0, stream>>>(x, noise, a1, tr, st, trT);
  gram2_kernel<<<2048, 256, 0, stream>>>(tr, st, AG, LbG);
  ff_kernel<<<dim3(512, 4), 256, 0, stream>>>(x, a2, Wproj, ffa, ffb, ffg, ffe, out);
  scan_kernel<<<16, 256, 0, stream>>>(tr, st, trT, AG, LbG, Wttt, out);
}

// Round 5
// 1902.796 us; speedup vs baseline: 2.7264x; 2.7264x over previous
//
#include <hip/hip_runtime.h>

typedef unsigned short u16;
typedef unsigned int u32;
typedef __attribute__((ext_vector_type(8))) short bf16x8;
typedef __attribute__((ext_vector_type(4))) float f32x4;

#define SB 16
#define SS 2048
#define SD 256
#define CC 16            // chunk length
#define NCH (SS / CC)    // 128 chunks
#define KAPPA 4.8828125e-6f   // 0.01 * 2/(16*256)
#define RP 24            // u16 pitch of transposed 16x16 publish tiles

__device__ __forceinline__ u16 f2bf(float f) {
  u32 u = __float_as_uint(f);
  u = (u + 0x7FFFu + ((u >> 16) & 1u)) >> 16;
  return (u16)u;
}
__device__ __forceinline__ float bf2f(u16 u) { return __uint_as_float((u32)u << 16); }

__device__ __forceinline__ bf16x8 ldfrag(const u16* p) {
  union { uint4 u; bf16x8 f; } cv;
  cv.u = *(const uint4*)p;
  return cv.f;
}
__device__ __forceinline__ bf16x8 asfrag(uint4 q) {
  union { uint4 u; bf16x8 f; } cv;
  cv.u = q;
  return cv.f;
}
__device__ __forceinline__ f32x4 mfma16(bf16x8 a, bf16x8 b, f32x4 c) {
  return __builtin_amdgcn_mfma_f32_16x16x32_bf16(a, b, c, 0, 0, 0);
}

// ---------------- prep: train/state (bf16 [t][b][d]) + trainT ([t][d][b]) ----
__global__ __launch_bounds__(256) void prep_kernel(
    const float* __restrict__ x, const float* __restrict__ noise,
    const float* __restrict__ a1,
    u16* __restrict__ train, u16* __restrict__ state, u16* __restrict__ trainT) {
  size_t i4 = (size_t)blockIdx.x * 256 + threadIdx.x;
  size_t base = i4 * 4;
  int d = (int)(base & 255);
  int t = (int)((base >> 8) & 2047);
  int b = (int)(base >> 19);
  float4 xv = *(const float4*)(x + base);
  float4 nv = *(const float4*)(noise + base);
  float4 av = *(const float4*)(a1 + d);
  float m0 = tanhf(av.x * xv.x);
  float m1 = tanhf(av.y * xv.y);
  float m2 = tanhf(av.z * xv.z);
  float m3 = tanhf(av.w * xv.w);
  size_t dst = ((size_t)t * SB + b) * SD + d;
  ushort4 tr, st;
  tr.x = f2bf(m0 + nv.x); tr.y = f2bf(m1 + nv.y);
  tr.z = f2bf(m2 + nv.z); tr.w = f2bf(m3 + nv.w);
  st.x = f2bf(m0); st.y = f2bf(m1); st.z = f2bf(m2); st.w = f2bf(m3);
  *(ushort4*)(train + dst) = tr;
  *(ushort4*)(state + dst) = st;
  size_t tb = ((size_t)t * SD + d) * SB + b;   // trainT[t][d][b]
  trainT[tb + 0 * SB] = tr.x;
  trainT[tb + 1 * SB] = tr.y;
  trainT[tb + 2 * SB] = tr.z;
  trainT[tb + 3 * SB] = tr.w;
}

// ---------------- gram2: AG[c][t][sp][16][32], LbG likewise (zero-filled) ----
__global__ __launch_bounds__(256) void gram2_kernel(
    const u16* __restrict__ tr, const u16* __restrict__ st,
    u16* __restrict__ AG, u16* __restrict__ LbG) {
  const int cb = blockIdx.x;        // c*16 + t
  const int c = cb >> 4, t = cb & 15;
  const int tid = threadIdx.x, lane = tid & 63, wv = tid >> 6;
  const int lr = lane & 15, lq = lane >> 4;
  const size_t Tt = (size_t)cb;
  bf16x8 trF[8], stF[8];
#pragma unroll
  for (int k = 0; k < 8; ++k) {
    trF[k] = ldfrag(tr + (Tt * 16 + lr) * 256 + k * 32 + lq * 8);
    stF[k] = ldfrag(st + (Tt * 16 + lr) * 256 + k * 32 + lq * 8);
  }
  for (int ii = 0; ii < 2; ++ii) {
    const int sp = wv + ii * 4;
    u16* dA = AG + ((size_t)cb * 8 + sp) * 512;
    u16* dL = LbG + ((size_t)cb * 8 + sp) * 512;
#pragma unroll
    for (int h = 0; h < 2; ++h) {
      const int s = 2 * sp + h;
      f32x4 accA = {0.f, 0.f, 0.f, 0.f}, accL = {0.f, 0.f, 0.f, 0.f};
      if (s <= t) {
        const u16* bsrc = tr + ((size_t)(c * 16 + s) * 16 + lr) * 256 + lq * 8;
#pragma unroll
        for (int k = 0; k < 8; ++k) {
          bf16x8 bk = ldfrag(bsrc + k * 32);
          if (s < t) accA = mfma16(trF[k], bk, accA);
          accL = mfma16(stF[k], bk, accL);
        }
      }
#pragma unroll
      for (int r = 0; r < 4; ++r) {
        int idx = (lq * 4 + r) * 32 + h * 16 + lr;
        dA[idx] = (s < t) ? f2bf(accA[r]) : (u16)0;
        dL[idx] = (s <= t) ? f2bf(accL[r]) : (u16)0;
      }
    }
  }
}

// ---------------- ff path: out = u .* (v @ Wp^T) + prev(out)  --------------
__global__ __launch_bounds__(256) void ff_kernel(
    const float* __restrict__ x, const float* __restrict__ a2,
    const float* __restrict__ Wp, const float* __restrict__ ffa,
    const float* __restrict__ ffb, const float* __restrict__ ffg_,
    const float* __restrict__ ffe_, float* __restrict__ out) {
  __shared__ float As[32][68];
  __shared__ float Bs[32][68];
  const int tid = threadIdx.x;
  const int gm0 = blockIdx.x * 64;
  const int gn0 = blockIdx.y * 64;
  const int tm = tid & 15, tn = tid >> 4;
  const int lr = tid & 63;
  const int lq = tid >> 6;
  float acc[4][4];
#pragma unroll
  for (int i = 0; i < 4; i++)
#pragma unroll
    for (int j = 0; j < 4; j++) acc[i][j] = 0.f;

  for (int k0 = 0; k0 < 256; k0 += 32) {
    {
      const float* xp = x + (size_t)(gm0 + lr) * 256 + k0 + lq * 8;
      float4 v0 = *(const float4*)(xp);
      float4 v1 = *(const float4*)(xp + 4);
      const float* ap = a2 + k0 + lq * 8;
      float4 a0 = *(const float4*)(ap);
      float4 a1v = *(const float4*)(ap + 4);
      As[lq * 8 + 0][lr] = tanhf(a0.x * v0.x);
      As[lq * 8 + 1][lr] = tanhf(a0.y * v0.y);
      As[lq * 8 + 2][lr] = tanhf(a0.z * v0.z);
      As[lq * 8 + 3][lr] = tanhf(a0.w * v0.w);
      As[lq * 8 + 4][lr] = tanhf(a1v.x * v1.x);
      As[lq * 8 + 5][lr] = tanhf(a1v.y * v1.y);
      As[lq * 8 + 6][lr] = tanhf(a1v.z * v1.z);
      As[lq * 8 + 7][lr] = tanhf(a1v.w * v1.w);
      const float* wp = Wp + (size_t)(gn0 + lr) * 256 + k0 + lq * 8;
      float4 w0 = *(const float4*)(wp);
      float4 w1 = *(const float4*)(wp + 4);
      Bs[lq * 8 + 0][lr] = w0.x; Bs[lq * 8 + 1][lr] = w0.y;
      Bs[lq * 8 + 2][lr] = w0.z; Bs[lq * 8 + 3][lr] = w0.w;
      Bs[lq * 8 + 4][lr] = w1.x; Bs[lq * 8 + 5][lr] = w1.y;
      Bs[lq * 8 + 6][lr] = w1.z; Bs[lq * 8 + 7][lr] = w1.w;
    }
    __syncthreads();
#pragma unroll
    for (int k = 0; k < 32; ++k) {
      float4 av4 = *(const float4*)&As[k][tm * 4];
      float4 bv4 = *(const float4*)&Bs[k][tn * 4];
      float a[4] = {av4.x, av4.y, av4.z, av4.w};
      float b[4] = {bv4.x, bv4.y, bv4.z, bv4.w};
#pragma unroll
      for (int i = 0; i < 4; i++)
#pragma unroll
        for (int j = 0; j < 4; j++) acc[i][j] += a[i] * b[j];
    }
    __syncthreads();
  }
  const float ga = ffg_[0], et = ffe_[0];
#pragma unroll
  for (int ii = 0; ii < 4; ++ii) {
    int row = gm0 + tm * 4 + ii;
    int col = gn0 + tn * 4;
    float4 xv = *(const float4*)(x + (size_t)row * 256 + col);
    float4 prev = *(const float4*)(out + (size_t)row * 256 + col);
    float4 fa = *(const float4*)(ffa + col);
    float4 fb = *(const float4*)(ffb + col);
    float4 a2v = *(const float4*)(a2 + col);
    float xs[4] = {xv.x, xv.y, xv.z, xv.w};
    float fas[4] = {fa.x, fa.y, fa.z, fa.w};
    float fbs[4] = {fb.x, fb.y, fb.z, fb.w};
    float a2s[4] = {a2v.x, a2v.y, a2v.z, a2v.w};
    float pv[4] = {prev.x, prev.y, prev.z, prev.w};
    float res[4];
#pragma unroll
    for (int j = 0; j < 4; ++j) {
      float v = tanhf(a2s[j] * xs[j]);
      float z = fas[j] * v;
      float gelu = 0.5f * z * (1.0f + erff(z * 0.70710678118654752f));
      float u = ga * gelu + et * sinf(fbs[j] * v);
      res[j] = u * acc[ii][j] + pv[j];
    }
    float4 o; o.x = res[0]; o.y = res[1]; o.z = res[2]; o.w = res[3];
    *(float4*)(out + (size_t)row * 256 + col) = o;
  }
}

// ---------------- scan: 16 WGs x 512 thr; wave w owns t=w and t=w+8 --------
__global__ __launch_bounds__(512, 1) void scan_kernel(
    const u16* __restrict__ tr, const u16* __restrict__ st,
    const u16* __restrict__ trT, const u16* __restrict__ AG,
    const u16* __restrict__ LbG, const float* __restrict__ Wttt,
    float* __restrict__ out) {
  __shared__ u16 RpL[CC][16 * RP];   // bf16(rhs) transposed [d1][b]
  __shared__ u16 Y1L[CC][16 * RP];
  __shared__ u16 DpL[CC][16 * RP];
  __shared__ u16 WbL[16][268];       // bf16 W block [d1][d], pitch 268
  __shared__ float WfL[16][268];     // f32 master

  const int tid = threadIdx.x;
  const int lane = tid & 63;
  const int w = tid >> 6;            // wave 0..7
  const int d1b = blockIdx.x;
  const int lr = lane & 15;
  const int lq = lane >> 4;

  for (int i = tid; i < 16 * 256; i += 512) {
    int r = i >> 8, d = i & 255;
    float wv_ = Wttt[(size_t)(d1b * 16 + r) * 256 + d];
    WfL[r][d] = wv_;
    WbL[r][d] = f2bf(wv_);
  }
  __syncthreads();

  for (int c = 0; c < NCH; ++c) {
    // ---- prefetch AG frags for both t's (used in P2 AND P3) ----
    uint4 agR[2][8];
#pragma unroll
    for (int u = 0; u < 2; ++u) {
      const u16* ag = AG + ((size_t)(c * 16 + w + 8 * u) * 8) * 512 + lr * 32 + lq * 8;
#pragma unroll
      for (int sp = 0; sp < 8; ++sp) agR[u][sp] = *(const uint4*)(ag + sp * 512);
    }
    // ---- P1 loads: tr/st frags + st scalars for both t's ----
    uint4 trR[2][8], stR[2][8];
    float sub[2][4];
#pragma unroll
    for (int u = 0; u < 2; ++u) {
      const size_t T = (size_t)c * CC + w + 8 * u;
      const u16* trt = tr + (T * 16 + lr) * 256 + lq * 8;
      const u16* stt = st + (T * 16 + lr) * 256 + lq * 8;
#pragma unroll
      for (int k = 0; k < 8; ++k) {
        trR[u][k] = *(const uint4*)(trt + k * 32);
        stR[u][k] = *(const uint4*)(stt + k * 32);
      }
#pragma unroll
      for (int r = 0; r < 4; ++r)
        sub[u][r] = bf2f(st[(T * 16 + lq * 4 + r) * 256 + d1b * 16 + lr]);
    }

    // ---- P1 compute: rhs = tr@W^T - st ; q = st@W^T ----
    f32x4 rhsF[2], qF[2];
#pragma unroll
    for (int u = 0; u < 2; ++u) {
      f32x4 racc = {0.f, 0.f, 0.f, 0.f}, qacc = {0.f, 0.f, 0.f, 0.f};
#pragma unroll
      for (int k = 0; k < 8; ++k) {
        bf16x8 wb = ldfrag(&WbL[lr][k * 32 + lq * 8]);
        racc = mfma16(asfrag(trR[u][k]), wb, racc);
        qacc = mfma16(asfrag(stR[u][k]), wb, qacc);
      }
#pragma unroll
      for (int r = 0; r < 4; ++r) racc[r] -= sub[u][r];
      rhsF[u] = racc; qF[u] = qacc;
      ushort4 pk;
      pk.x = f2bf(racc.x); pk.y = f2bf(racc.y);
      pk.z = f2bf(racc.z); pk.w = f2bf(racc.w);
      *(ushort4*)(&RpL[w + 8 * u][lr * RP + lq * 4]) = pk;
    }
    __syncthreads();  // b1

    // ---- prefetch LbG frags (used in P4) ----
    uint4 lbR[2][8];
#pragma unroll
    for (int u = 0; u < 2; ++u) {
      const u16* lb = LbG + ((size_t)(c * 16 + w + 8 * u) * 8) * 512 + lr * 32 + lq * 8;
#pragma unroll
      for (int sp = 0; sp < 8; ++sp) lbR[u][sp] = *(const uint4*)(lb + sp * 512);
    }

    // ---- P2: y1 = A @ rhs ----
    f32x4 y1F[2];
#pragma unroll
    for (int u = 0; u < 2; ++u) {
      f32x4 acc = {0.f, 0.f, 0.f, 0.f};
#pragma unroll
      for (int sp = 0; sp < 8; ++sp) {
        bf16x8 bf = ldfrag(&RpL[2 * sp + (lq >> 1)][lr * RP + (lq & 1) * 8]);
        acc = mfma16(asfrag(agR[u][sp]), bf, acc);
      }
      y1F[u] = acc;
      ushort4 pk;
      pk.x = f2bf(acc.x); pk.y = f2bf(acc.y);
      pk.z = f2bf(acc.z); pk.w = f2bf(acc.w);
      *(ushort4*)(&Y1L[w + 8 * u][lr * RP + lq * 4]) = pk;
    }
    __syncthreads();  // b2

    // ---- P3: y2 = A @ y1; Dp = -kappa*(rhs - k*y1 + k^2*y2) ----
#pragma unroll
    for (int u = 0; u < 2; ++u) {
      f32x4 acc = {0.f, 0.f, 0.f, 0.f};
#pragma unroll
      for (int sp = 0; sp < 8; ++sp) {
        bf16x8 bf = ldfrag(&Y1L[2 * sp + (lq >> 1)][lr * RP + (lq & 1) * 8]);
        acc = mfma16(asfrag(agR[u][sp]), bf, acc);
      }
      ushort4 pk;
#pragma unroll
      for (int r = 0; r < 4; ++r) {
        float dv = rhsF[u][r] - KAPPA * y1F[u][r] + (KAPPA * KAPPA) * acc[r];
        ((u16*)&pk)[r] = f2bf(-KAPPA * dv);
      }
      *(ushort4*)(&DpL[w + 8 * u][lr * RP + lq * 4]) = pk;
    }
    __syncthreads();  // b3

    // ---- P4a: Out = q + Lb @ Dp ; plain store ----
#pragma unroll
    for (int u = 0; u < 2; ++u) {
      const size_t T = (size_t)c * CC + w + 8 * u;
      f32x4 acc = qF[u];
#pragma unroll
      for (int sp = 0; sp < 8; ++sp) {
        bf16x8 bf = ldfrag(&DpL[2 * sp + (lq >> 1)][lr * RP + (lq & 1) * 8]);
        acc = mfma16(asfrag(lbR[u][sp]), bf, acc);
      }
#pragma unroll
      for (int r = 0; r < 4; ++r) {
        size_t oi = ((size_t)(lq * 4 + r) * SS + T) * SD + d1b * 16 + lr;
        out[oi] = acc[r];
      }
    }

    // ---- P4b: dW = Dp^T-stack @ trT ; apply to WfL and WbL ----
    bf16x8 afR[8];
#pragma unroll
    for (int sp = 0; sp < 8; ++sp)
      afR[sp] = ldfrag(&DpL[2 * sp + (lq >> 1)][lr * RP + (lq & 1) * 8]);
#pragma unroll
    for (int u = 0; u < 2; ++u) {
      const int d2b = w + 8 * u;
      f32x4 acc = {0.f, 0.f, 0.f, 0.f};
#pragma unroll
      for (int sp = 0; sp < 8; ++sp) {
        const int s0 = 2 * sp + (lq >> 1);
        bf16x8 bf = ldfrag(trT + ((size_t)(c * CC + s0) * 256 + d2b * 16 + lr) * 16 +
                           (lq & 1) * 8);
        acc = mfma16(afR[sp], bf, acc);
      }
#pragma unroll
      for (int r = 0; r < 4; ++r) {
        float nw = WfL[lq * 4 + r][d2b * 16 + lr] + acc[r];
        WfL[lq * 4 + r][d2b * 16 + lr] = nw;
        WbL[lq * 4 + r][d2b * 16 + lr] = f2bf(nw);
      }
    }
    __syncthreads();  // b4: W ready for next chunk
  }
}

extern "C" void kernel_launch(void* const* d_in, const int* in_sizes, int n_in,
                              void* d_out, int out_size, void* d_ws, size_t ws_size,
                              hipStream_t stream) {
  const float* x     = (const float*)d_in[0];
  const float* noise = (const float*)d_in[1];
  const float* a1    = (const float*)d_in[2];
  const float* a2    = (const float*)d_in[3];
  const float* Wttt  = (const float*)d_in[4];
  const float* Wproj = (const float*)d_in[5];
  const float* ffa   = (const float*)d_in[6];
  const float* ffb   = (const float*)d_in[7];
  const float* ffg   = (const float*)d_in[8];
  const float* ffe   = (const float*)d_in[9];
  float* out = (float*)d_out;

  const size_t N = (size_t)SB * SS * SD;   // 8388608 elements
  u16* tr  = (u16*)d_ws;
  u16* st  = tr + N;
  u16* trT = st + N;
  u16* AG  = trT + N;
  u16* LbG = AG + N;    // total ws = 5N*2B ~ 84MB

  prep_kernel<<<8192, 256, 0, stream>>>(x, noise, a1, tr, st, trT);
  gram2_kernel<<<2048, 256, 0, stream>>>(tr, st, AG, LbG);
  scan_kernel<<<16, 512, 0, stream>>>(tr, st, trT, AG, LbG, Wttt, out);
  ff_kernel<<<dim3(512, 4), 256, 0, stream>>>(x, a2, Wproj, ffa, ffb, ffg, ffe, out);
}